// Round 6
// baseline (135.437 us; speedup 1.0000x reference)
//
#include <hip/hip_runtime.h>
#include <hip/hip_fp16.h>

#define IN_F   100000
#define OUT_F  100000
#define NNZ_N  1600000
#define TC     256
#define TBLK   ((IN_F + TC - 1) / TC)      // 391 transpose blocks
#define SBLK   ((NNZ_N + 255) / 256)       // 6250 scan/pack blocks

__device__ __forceinline__ float2 h2f(unsigned u) {
    const __half2 h = *reinterpret_cast<const __half2*>(&u);
    return __half22float2(h);
}

// ---------------------------------------------------------------------------
// Prep (fused): blocks [0,TBLK) transpose x (64,IN) f32 -> xh (IN,64) f16
// (u32 index: col*32 + pair). Blocks [TBLK,TBLK+SBLK): rowstart linear scan
// over sorted rows + (col,val) -> uint2 pack.
// ---------------------------------------------------------------------------
__global__ __launch_bounds__(256) void k_prep(
    const float* __restrict__ x,
    const int*   __restrict__ rows,
    const int*   __restrict__ cols,
    const float* __restrict__ vals,
    unsigned* __restrict__ xh,
    int*      __restrict__ rstart,
    uint2*    __restrict__ pairs) {
    __shared__ unsigned tile[TC][33];
    const int bid = blockIdx.x;
    const int t   = threadIdx.x;

    if (bid < TBLK) {
        const int i0   = bid * TC;
        const int colr = i0 + t;
        if (colr < IN_F) {
            #pragma unroll 8
            for (int p = 0; p < 32; ++p) {
                const float a = x[(size_t)(2 * p)     * IN_F + colr];
                const float b = x[(size_t)(2 * p + 1) * IN_F + colr];
                const __half2 h = __floats2half2_rn(a, b);
                tile[t][p] = *reinterpret_cast<const unsigned*>(&h);
            }
        }
        __syncthreads();
        const int u  = t & 31;
        const int c8 = t >> 5;
        for (int cc = c8; cc < TC; cc += 8) {
            const int col = i0 + cc;
            if (col < IN_F)
                xh[(size_t)col * 32 + u] = tile[cc][u];
        }
    } else {
        const int e = (bid - TBLK) * 256 + t;
        if (e >= NNZ_N) return;
        const int cur  = rows[e];
        const int prev = (e == 0) ? -1 : rows[e - 1];
        for (int r = prev + 1; r <= cur; ++r) rstart[r] = e;
        if (e == NNZ_N - 1)
            for (int r = cur + 1; r <= OUT_F; ++r) rstart[r] = NNZ_N;
        pairs[e] = make_uint2((unsigned)cols[e], __float_as_uint(vals[e]));
    }
}

// ---------------------------------------------------------------------------
// SpMM: block = 256 threads = 4 waves = 64 rows. Each 8-lane group owns TWO
// rows with interleaved unroll-4 chains -> 8 independent gather lines per
// group per iteration = 64 lines in flight per wave. Lane sub loads uint4 =
// 8 halves = batches 8sub..8sub+7. All pairs-loads then all gathers issued
// before FMAs. fp32 accumulate.
// ---------------------------------------------------------------------------
__global__ __launch_bounds__(256, 4) void k_spmm(
    const uint4* __restrict__ xh4,        // col*8 + sub
    const uint2* __restrict__ pairs,
    const int*   __restrict__ rstart_g,
    const float* __restrict__ bias,
    float* __restrict__ out) {
    __shared__ int   rs[65];
    __shared__ float tile[64][65];
    const int r0   = blockIdx.x * 64;
    const int t    = threadIdx.x;
    const int lane = t & 63;
    const int w    = t >> 6;              // 0..3

    if (t < 65) {
        int idx = r0 + t; if (idx > OUT_F) idx = OUT_F;
        rs[t] = rstart_g[idx];
    }
    __syncthreads();

    const int g   = lane >> 3;            // group [0,8)
    const int sub = lane & 7;             // batch octet
    const int gid = (w << 3) + g;         // [0,32)
    const int lj0 = gid << 1;             // two local rows
    const int lj1 = lj0 + 1;

    const int s0 = rs[lj0], e0 = rs[lj0 + 1];
    const int s1 = rs[lj1], e1 = rs[lj1 + 1];
    // safe clamp element for exhausted/empty rows (always a valid index)
    int c0m = e0 - 1; if (c0m < s0) c0m = s0; if (c0m > NNZ_N - 1) c0m = NNZ_N - 1;
    int c1m = e1 - 1; if (c1m < s1) c1m = s1; if (c1m > NNZ_N - 1) c1m = NNZ_N - 1;

    const int n0 = e0 - s0, n1 = e1 - s1;
    const int nmax = (n0 > n1) ? n0 : n1;

    float acc0[8], acc1[8];
    #pragma unroll
    for (int i = 0; i < 8; ++i) { acc0[i] = 0.f; acc1[i] = 0.f; }

    for (int k = 0; k < nmax; k += 4) {
        uint2 p0[4], p1[4];
        float v0[4], v1[4];
        // issue all 8 pairs loads
        #pragma unroll
        for (int u = 0; u < 4; ++u) {
            const int i0 = s0 + k + u;
            const int i1 = s1 + k + u;
            p0[u] = pairs[(i0 < e0) ? i0 : c0m];
            p1[u] = pairs[(i1 < e1) ? i1 : c1m];
        }
        #pragma unroll
        for (int u = 0; u < 4; ++u) {
            v0[u] = (s0 + k + u < e0) ? __uint_as_float(p0[u].y) : 0.f;
            v1[u] = (s1 + k + u < e1) ? __uint_as_float(p1[u].y) : 0.f;
        }
        // issue all 8 gathers
        uint4 g0[4], g1[4];
        #pragma unroll
        for (int u = 0; u < 4; ++u) g0[u] = xh4[(size_t)p0[u].x * 8 + sub];
        #pragma unroll
        for (int u = 0; u < 4; ++u) g1[u] = xh4[(size_t)p1[u].x * 8 + sub];
        // FMAs
        #pragma unroll
        for (int u = 0; u < 4; ++u) {
            float2 f;
            f = h2f(g0[u].x); acc0[0] = fmaf(v0[u], f.x, acc0[0]); acc0[1] = fmaf(v0[u], f.y, acc0[1]);
            f = h2f(g0[u].y); acc0[2] = fmaf(v0[u], f.x, acc0[2]); acc0[3] = fmaf(v0[u], f.y, acc0[3]);
            f = h2f(g0[u].z); acc0[4] = fmaf(v0[u], f.x, acc0[4]); acc0[5] = fmaf(v0[u], f.y, acc0[5]);
            f = h2f(g0[u].w); acc0[6] = fmaf(v0[u], f.x, acc0[6]); acc0[7] = fmaf(v0[u], f.y, acc0[7]);
            f = h2f(g1[u].x); acc1[0] = fmaf(v1[u], f.x, acc1[0]); acc1[1] = fmaf(v1[u], f.y, acc1[1]);
            f = h2f(g1[u].y); acc1[2] = fmaf(v1[u], f.x, acc1[2]); acc1[3] = fmaf(v1[u], f.y, acc1[3]);
            f = h2f(g1[u].z); acc1[4] = fmaf(v1[u], f.x, acc1[4]); acc1[5] = fmaf(v1[u], f.y, acc1[5]);
            f = h2f(g1[u].w); acc1[6] = fmaf(v1[u], f.x, acc1[6]); acc1[7] = fmaf(v1[u], f.y, acc1[7]);
        }
    }

    #pragma unroll
    for (int i = 0; i < 8; ++i) {
        tile[lj0][(sub << 3) + i] = acc0[i];
        tile[lj1][(sub << 3) + i] = acc1[i];
    }
    __syncthreads();

    const int rc = r0 + lane;
    if (rc < OUT_F) {
        const float bv = bias[rc];
        for (int bb = w; bb < 64; bb += 4)
            out[(size_t)bb * OUT_F + rc] = tile[lane][bb] + bv;
    }
}

// ---------------------------------------------------------------------------
// Fallback (insufficient ws): gather from native x layout. Correct, slow.
// ---------------------------------------------------------------------------
__global__ __launch_bounds__(256) void k_spmm_fallback(
    const float* __restrict__ x,
    const float* __restrict__ vals,
    const int*   __restrict__ rows,
    const int*   __restrict__ cols,
    const float* __restrict__ bias,
    float* __restrict__ out) {
    __shared__ int   rstart[65];
    __shared__ float tile[64][65];
    const int r0   = blockIdx.x * 64;
    const int t    = threadIdx.x;
    const int lane = t & 63;
    const int w    = t >> 6;
    if (t < 65) {
        const int target = r0 + t;
        int lo = 0, hi = NNZ_N;
        while (lo < hi) {
            const int mid = (lo + hi) >> 1;
            if (rows[mid] < target) lo = mid + 1; else hi = mid;
        }
        rstart[t] = lo;
    }
    __syncthreads();
    for (int j = w; j < 64; j += 4) {
        const int s = rstart[j], e = rstart[j + 1];
        float acc = 0.f;
        const size_t base = (size_t)lane * IN_F;
        for (int idx = s; idx < e; ++idx)
            acc = fmaf(vals[idx], x[base + cols[idx]], acc);
        tile[j][lane] = acc;
    }
    __syncthreads();
    const int c = lane;
    if (r0 + c < OUT_F) {
        const float bv = bias[r0 + c];
        for (int bb = w; bb < 64; bb += 4)
            out[(size_t)bb * OUT_F + (r0 + c)] = tile[c][bb] + bv;
    }
}

extern "C" void kernel_launch(void* const* d_in, const int* in_sizes, int n_in,
                              void* d_out, int out_size, void* d_ws, size_t ws_size,
                              hipStream_t stream) {
    const float* x      = (const float*)d_in[0];
    const float* values = (const float*)d_in[1];
    const float* bias   = (const float*)d_in[2];
    const int*   rows   = (const int*)d_in[3];
    const int*   cols   = (const int*)d_in[4];
    float*       out    = (float*)d_out;

    const size_t xh_bytes = (size_t)IN_F * 32 * sizeof(unsigned);   // 12.8 MB
    const size_t rs_off   = (xh_bytes + 255) & ~(size_t)255;
    const size_t rs_bytes = (size_t)(OUT_F + 1) * sizeof(int);
    const size_t pr_off   = (rs_off + rs_bytes + 255) & ~(size_t)255;
    const size_t need     = pr_off + (size_t)NNZ_N * sizeof(uint2); // ~26 MB

    const int row_blocks = (OUT_F + 63) / 64;   // 1563

    if (ws_size >= need) {
        unsigned* xh     = (unsigned*)d_ws;
        int*      rstart = (int*)((char*)d_ws + rs_off);
        uint2*    pairs  = (uint2*)((char*)d_ws + pr_off);
        k_prep<<<TBLK + SBLK, 256, 0, stream>>>(x, rows, cols, values, xh, rstart, pairs);
        k_spmm<<<row_blocks, 256, 0, stream>>>(
            (const uint4*)xh, pairs, rstart, bias, out);
    } else {
        k_spmm_fallback<<<row_blocks, 256, 0, stream>>>(x, values, rows, cols, bias, out);
    }
}